// Round 1
// baseline (1266.009 us; speedup 1.0000x reference)
//
#include <hip/hip_runtime.h>
#include <math.h>

// Constants of the problem
#define H_   768
#define NH_  4
#define HD_  192
#define E_   9
#define R_   12
#define D_   64
#define B_   4
#define S_   1024
#define H3_  (3 * H_)

static const long OUT_REL_OFF = (long)B_ * E_ * S_ * S_;                    // 37,748,736
static const long OUT_ENH_OFF = OUT_REL_OFF + (long)B_ * R_ * S_ * S_;      // 88,080,384

// ---------------------------------------------------------------------------
// Generic tiled GEMM:  C[m,n] = sum_k A[m,k] * B[n,k]   (NT form, both K-contig)
// 64x64 tile, 256 threads, 4x4 microtile, BK=16, k-major LDS.
// Batched over blockIdx.z: z -> (zb = z/nh, zh = z%nh), per-component strides.
// EPI==0: +bias (optional). EPI==1: gp_matrix logits epilogue (mask/tril/scale).
// ---------------------------------------------------------------------------
template<int EPI>
__global__ __launch_bounds__(256) void gemm_nt(
    const float* __restrict__ A, const float* __restrict__ Bw,
    const float* __restrict__ bias, float* __restrict__ C,
    int K, int lda, int ldb, int ldc, int nh,
    long sAb, long sAh, long sBb, long sBh, long sCb, long sCh,
    const float* __restrict__ mask)
{
    const int z = blockIdx.z;
    const int zb = z / nh, zh = z - zb * nh;
    A  += (long)zb * sAb + (long)zh * sAh;
    Bw += (long)zb * sBb + (long)zh * sBh;
    C  += (long)zb * sCb + (long)zh * sCh;
    if (EPI == 1) mask += (long)zb * S_;

    const int m0 = blockIdx.y * 64, n0 = blockIdx.x * 64;
    __shared__ float As[16][64];
    __shared__ float Bs[16][64];
    const int tid = threadIdx.x;
    const int lr = tid >> 2, lc = (tid & 3) << 2;   // loader: row lr, cols lc..lc+3
    const int tx = tid & 15, ty = tid >> 4;         // compute: 4x4 at (ty*4, tx*4)
    const float* Arow = A + (long)(m0 + lr) * lda + lc;
    const float* Brow = Bw + (long)(n0 + lr) * ldb + lc;
    float acc[4][4] = {};
    for (int k0 = 0; k0 < K; k0 += 16) {
        float4 av = *reinterpret_cast<const float4*>(Arow + k0);
        float4 bv = *reinterpret_cast<const float4*>(Brow + k0);
        As[lc + 0][lr] = av.x; As[lc + 1][lr] = av.y;
        As[lc + 2][lr] = av.z; As[lc + 3][lr] = av.w;
        Bs[lc + 0][lr] = bv.x; Bs[lc + 1][lr] = bv.y;
        Bs[lc + 2][lr] = bv.z; Bs[lc + 3][lr] = bv.w;
        __syncthreads();
        #pragma unroll
        for (int kk = 0; kk < 16; ++kk) {
            float4 a4 = *reinterpret_cast<const float4*>(&As[kk][ty << 2]);
            float4 b4 = *reinterpret_cast<const float4*>(&Bs[kk][tx << 2]);
            float aa[4] = {a4.x, a4.y, a4.z, a4.w};
            float bb[4] = {b4.x, b4.y, b4.z, b4.w};
            #pragma unroll
            for (int i = 0; i < 4; ++i)
                #pragma unroll
                for (int j = 0; j < 4; ++j)
                    acc[i][j] = fmaf(aa[i], bb[j], acc[i][j]);
        }
        __syncthreads();
    }
    #pragma unroll
    for (int i = 0; i < 4; ++i) {
        const int gm = m0 + (ty << 2) + i;
        #pragma unroll
        for (int j = 0; j < 4; ++j) {
            const int gn = n0 + (tx << 2) + j;
            float v = acc[i][j];
            if (EPI == 0) {
                if (bias) v += bias[gn];
            } else {
                const float pad = mask[gn];
                v = v * pad - (1.0f - pad) * 1e12f;
                if (gm > gn) v -= 1e12f;
                v *= 0.125f;                       // 1/sqrt(D=64)
            }
            C[(long)gm * ldc + gn] = v;
        }
    }
}

// ---------------------------------------------------------------------------
// NN GEMM: C[m,n] = sum_k A[m,k] * B[k,n]  (for attn @ V). Same tiling.
// ---------------------------------------------------------------------------
__global__ __launch_bounds__(256) void gemm_nn(
    const float* __restrict__ A, const float* __restrict__ Bw,
    float* __restrict__ C,
    int K, int lda, int ldb, int ldc, int nh,
    long sAb, long sAh, long sBb, long sBh, long sCb, long sCh)
{
    const int z = blockIdx.z;
    const int zb = z / nh, zh = z - zb * nh;
    A  += (long)zb * sAb + (long)zh * sAh;
    Bw += (long)zb * sBb + (long)zh * sBh;
    C  += (long)zb * sCb + (long)zh * sCh;

    const int m0 = blockIdx.y * 64, n0 = blockIdx.x * 64;
    __shared__ float As[16][64];
    __shared__ float Bs[16][64];
    const int tid = threadIdx.x;
    const int lr = tid >> 2, lc = (tid & 3) << 2;       // A loader
    const int rB = tid >> 4, cB = (tid & 15) << 2;      // B loader (16 k-rows x 64 n-cols)
    const int tx = tid & 15, ty = tid >> 4;
    const float* Arow = A + (long)(m0 + lr) * lda + lc;
    float acc[4][4] = {};
    for (int k0 = 0; k0 < K; k0 += 16) {
        float4 av = *reinterpret_cast<const float4*>(Arow + k0);
        float4 bv = *reinterpret_cast<const float4*>(Bw + (long)(k0 + rB) * ldb + n0 + cB);
        As[lc + 0][lr] = av.x; As[lc + 1][lr] = av.y;
        As[lc + 2][lr] = av.z; As[lc + 3][lr] = av.w;
        *reinterpret_cast<float4*>(&Bs[rB][cB]) = bv;
        __syncthreads();
        #pragma unroll
        for (int kk = 0; kk < 16; ++kk) {
            float4 a4 = *reinterpret_cast<const float4*>(&As[kk][ty << 2]);
            float4 b4 = *reinterpret_cast<const float4*>(&Bs[kk][tx << 2]);
            float aa[4] = {a4.x, a4.y, a4.z, a4.w};
            float bb[4] = {b4.x, b4.y, b4.z, b4.w};
            #pragma unroll
            for (int i = 0; i < 4; ++i)
                #pragma unroll
                for (int j = 0; j < 4; ++j)
                    acc[i][j] = fmaf(aa[i], bb[j], acc[i][j]);
        }
        __syncthreads();
    }
    #pragma unroll
    for (int i = 0; i < 4; ++i) {
        const int gm = m0 + (ty << 2) + i;
        #pragma unroll
        for (int j = 0; j < 4; ++j) {
            const int gn = n0 + (tx << 2) + j;
            C[(long)gm * ldc + gn] = acc[i][j];
        }
    }
}

// ---------------------------------------------------------------------------
// Row softmax with scale + key_pad mask. One block per row of S_ columns.
// ---------------------------------------------------------------------------
__global__ __launch_bounds__(256) void softmax_rows(
    float* __restrict__ P, const float* __restrict__ mask)
{
    const long row = blockIdx.x;                 // (b*NH + h)*S + q
    const int b = (int)(row / ((long)NH_ * S_));
    float* p = P + row * (long)S_;
    const float* mrow = mask + (long)b * S_;
    const int tid = threadIdx.x;
    const float scale = 1.0f / sqrtf((float)HD_);

    float v[4];
    float mx = -1e30f;
    #pragma unroll
    for (int j = 0; j < 4; ++j) {
        const int k = tid + j * 256;
        float s = p[k] * scale;
        if (mrow[k] == 0.0f) s = -1e9f;
        v[j] = s;
        mx = fmaxf(mx, s);
    }
    __shared__ float sm[4];
    #pragma unroll
    for (int o = 32; o > 0; o >>= 1) mx = fmaxf(mx, __shfl_down(mx, o, 64));
    const int lane = tid & 63, wid = tid >> 6;
    if (lane == 0) sm[wid] = mx;
    __syncthreads();
    mx = fmaxf(fmaxf(sm[0], sm[1]), fmaxf(sm[2], sm[3]));
    __syncthreads();
    float sum = 0.0f;
    #pragma unroll
    for (int j = 0; j < 4; ++j) { v[j] = expf(v[j] - mx); sum += v[j]; }
    #pragma unroll
    for (int o = 32; o > 0; o >>= 1) sum += __shfl_down(sum, o, 64);
    if (lane == 0) sm[wid] = sum;
    __syncthreads();
    sum = sm[0] + sm[1] + sm[2] + sm[3];
    const float inv = 1.0f / sum;
    #pragma unroll
    for (int j = 0; j < 4; ++j) p[tid + j * 256] = v[j] * inv;
}

// ---------------------------------------------------------------------------
// x = hs + sigmoid(gate_lin) * attn_out ; LayerNorm -> enhanced (d_out)
// One block per row (H_=768 = 3*256 cols).
// ---------------------------------------------------------------------------
__global__ __launch_bounds__(256) void gate_ln(
    const float* __restrict__ hs, const float* __restrict__ ao,
    const float* __restrict__ gl, const float* __restrict__ g,
    const float* __restrict__ bta, float* __restrict__ out)
{
    const long row = blockIdx.x;
    const float* hrow = hs + row * H_;
    const float* arow = ao + row * H_;
    const float* grow = gl + row * H_;
    const int tid = threadIdx.x;
    float x[3];
    float sum = 0.0f, sq = 0.0f;
    #pragma unroll
    for (int i = 0; i < 3; ++i) {
        const int j = tid + i * 256;
        const float a = arow[j];
        const float gt = 1.0f / (1.0f + expf(-grow[j]));
        const float xv = hrow[j] + gt * a;
        x[i] = xv; sum += xv; sq += xv * xv;
    }
    __shared__ float sm[8];
    #pragma unroll
    for (int o = 32; o > 0; o >>= 1) {
        sum += __shfl_down(sum, o, 64);
        sq  += __shfl_down(sq, o, 64);
    }
    const int lane = tid & 63, wid = tid >> 6;
    if (lane == 0) { sm[wid] = sum; sm[4 + wid] = sq; }
    __syncthreads();
    sum = sm[0] + sm[1] + sm[2] + sm[3];
    sq  = sm[4] + sm[5] + sm[6] + sm[7];
    const float mu  = sum * (1.0f / (float)H_);
    float var = sq * (1.0f / (float)H_) - mu * mu;
    var = fmaxf(var, 0.0f);
    const float inv = 1.0f / sqrtf(var + 1e-5f);
    #pragma unroll
    for (int i = 0; i < 3; ++i) {
        const int j = tid + i * 256;
        out[row * H_ + j] = (x[i] - mu) * inv * g[j] + bta[j];
    }
}

// ---------------------------------------------------------------------------
// In-place interleaved RoPE on (B,S,T,2D) buffer; both q (cols 0..63) and
// k (cols 64..127) halves rotated with the same per-half pair angles.
// ---------------------------------------------------------------------------
__global__ __launch_bounds__(256) void rope_rot(
    float* __restrict__ buf, int T, long total)
{
    const long gid = (long)blockIdx.x * blockDim.x + threadIdx.x;
    if (gid >= total) return;
    const int pidx = (int)(gid & 63);        // pair slot within 128-wide row
    const long rowIdx = gid >> 6;            // (b*S + s)*T + t
    const int half = pidx >> 5, ip = pidx & 31;
    const int c0 = half * 64 + ip * 2;
    const int s = (int)((rowIdx / T) % S_);
    const float inv = powf(10000.0f, -(float)ip * (1.0f / 32.0f));
    const float ang = (float)s * inv;
    float sn, cs;
    sincosf(ang, &sn, &cs);
    float* p = buf + rowIdx * 128 + c0;
    const float x0 = p[0], x1 = p[1];
    p[0] = x0 * cs - x1 * sn;
    p[1] = x1 * cs + x0 * sn;
}

// ---------------------------------------------------------------------------
// ent_prior: row max over final ent_logits. One block per (b,t,m) row.
// Writes transposed into prior[(b*S+m)*E + t].
// ---------------------------------------------------------------------------
__global__ __launch_bounds__(256) void rowmax_ent(
    const float* __restrict__ ent, float* __restrict__ prior)
{
    const long row = blockIdx.x;             // (b*E + t)*S + m
    const float* p = ent + row * (long)S_;
    const int tid = threadIdx.x;
    float mx = -INFINITY;
    #pragma unroll
    for (int j = 0; j < 4; ++j) mx = fmaxf(mx, p[tid + j * 256]);
    __shared__ float sm[4];
    #pragma unroll
    for (int o = 32; o > 0; o >>= 1) mx = fmaxf(mx, __shfl_down(mx, o, 64));
    const int lane = tid & 63, wid = tid >> 6;
    if (lane == 0) sm[wid] = mx;
    __syncthreads();
    if (tid == 0) {
        mx = fmaxf(fmaxf(sm[0], sm[1]), fmaxf(sm[2], sm[3]));
        const long b = row / ((long)E_ * S_);
        const long rem = row - b * E_ * S_;
        const int t = (int)(rem / S_);
        const int m = (int)(rem - (long)t * S_);
        prior[((long)b * S_ + m) * E_ + t] = mx;
    }
}

// ---------------------------------------------------------------------------
// rel_hidden = concat([enhanced, relu(prior @ prior_w.T + prior_b)], -1)
// ---------------------------------------------------------------------------
__global__ __launch_bounds__(256) void prior_concat(
    const float* __restrict__ enh, const float* __restrict__ prior,
    const float* __restrict__ pw, const float* __restrict__ pb,
    float* __restrict__ relh, long total)
{
    const long idx = (long)blockIdx.x * blockDim.x + threadIdx.x;
    if (idx >= total) return;
    const long row = idx / (2 * H_);
    const int c = (int)(idx - row * (2 * H_));
    if (c < H_) {
        relh[idx] = enh[row * H_ + c];
    } else {
        const int j = c - H_;
        float a = pb[j];
        const float* pr = prior + row * E_;
        #pragma unroll
        for (int e = 0; e < E_; ++e) a += pr[e] * pw[j * E_ + e];
        relh[idx] = fmaxf(a, 0.0f);
    }
}

// ---------------------------------------------------------------------------
extern "C" void kernel_launch(void* const* d_in, const int* in_sizes, int n_in,
                              void* d_out, int out_size, void* d_ws, size_t ws_size,
                              hipStream_t stream)
{
    const float* hs   = (const float*)d_in[0];
    const float* mask = (const float*)d_in[1];
    const float* ipw  = (const float*)d_in[2];
    const float* ipb  = (const float*)d_in[3];
    const float* opw  = (const float*)d_in[4];
    const float* opb  = (const float*)d_in[5];
    const float* gw   = (const float*)d_in[6];
    const float* gb   = (const float*)d_in[7];
    const float* lng  = (const float*)d_in[8];
    const float* lnb  = (const float*)d_in[9];
    const float* entw = (const float*)d_in[10];
    const float* entb = (const float*)d_in[11];
    const float* prw  = (const float*)d_in[12];
    const float* prb  = (const float*)d_in[13];
    const float* relw = (const float*)d_in[14];
    const float* relb = (const float*)d_in[15];
    float* out = (float*)d_out;
    float* ws  = (float*)d_ws;

    const int MBS = B_ * S_;                 // 4096 rows

    // Workspace layout (floats), with region reuse:
    float* qkv      = ws + 0;                // 9,437,184  (dead after ctx)
    float* scores   = ws + 9437184;          // 16,777,216 (dead after ctx)
    float* ctx      = ws + 26214400;         // 3,145,728
    float* attn_out = ws + 0;                // reuse qkv region
    float* gatelin  = ws + 3145728;          // reuse qkv region
    float* proj     = ws + 9437184;          // reuse scores region (<= 6,291,456)
    float* relh     = ws + 15728640;         // reuse scores region (6,291,456)
    float* prior    = ws + 22020096;         // reuse scores region (36,864)
    float* enh      = out + OUT_ENH_OFF;     // enhanced is output #2

    // 1. qkv = hs @ in_proj_w.T + in_proj_b           (4096 x 2304, K=768)
    gemm_nt<0><<<dim3(H3_ / 64, MBS / 64, 1), 256, 0, stream>>>(
        hs, ipw, ipb, qkv, H_, H_, H_, H3_, 1, 0, 0, 0, 0, 0, 0, nullptr);

    // 2. scores[b,h] = q @ k^T                        (16 x 1024 x 1024, K=192)
    gemm_nt<0><<<dim3(S_ / 64, S_ / 64, B_ * NH_), 256, 0, stream>>>(
        qkv, qkv + H_, nullptr, scores, HD_, H3_, H3_, S_, NH_,
        (long)S_ * H3_, HD_, (long)S_ * H3_, HD_,
        (long)NH_ * S_ * S_, (long)S_ * S_, nullptr);

    // 3. softmax rows (scale + key_pad)
    softmax_rows<<<B_ * NH_ * S_, 256, 0, stream>>>(scores, mask);

    // 4. ctx[b,h] = P @ V                             (16 x 1024 x 192, K=1024)
    gemm_nn<<<dim3(HD_ / 64, S_ / 64, B_ * NH_), 256, 0, stream>>>(
        scores, qkv + 2 * H_, ctx, S_, S_, H3_, H_, NH_,
        (long)NH_ * S_ * S_, (long)S_ * S_, (long)S_ * H3_, HD_,
        (long)S_ * H_, HD_);

    // 5. attn_out = ctx @ out_proj_w.T + b            (4096 x 768, K=768)
    gemm_nt<0><<<dim3(H_ / 64, MBS / 64, 1), 256, 0, stream>>>(
        ctx, opw, opb, attn_out, H_, H_, H_, H_, 1, 0, 0, 0, 0, 0, 0, nullptr);

    // 6. gate_lin = attn_out @ gate_w.T + b
    gemm_nt<0><<<dim3(H_ / 64, MBS / 64, 1), 256, 0, stream>>>(
        attn_out, gw, gb, gatelin, H_, H_, H_, H_, 1, 0, 0, 0, 0, 0, 0, nullptr);

    // 7. enhanced = LN(hs + sigmoid(gate_lin)*attn_out)
    gate_ln<<<MBS, 256, 0, stream>>>(hs, attn_out, gatelin, lng, lnb, enh);

    // 8. ent projection                                (4096 x 1152, K=768)
    gemm_nt<0><<<dim3((E_ * 2 * D_) / 64, MBS / 64, 1), 256, 0, stream>>>(
        enh, entw, entb, proj, H_, H_, H_, E_ * 2 * D_, 1, 0, 0, 0, 0, 0, 0, nullptr);

    // 9. RoPE rotate ent projection in place
    rope_rot<<<(int)(((long)MBS * E_ * 64) / 256), 256, 0, stream>>>(
        proj, E_, (long)MBS * E_ * 64);

    // 10. ent logits -> d_out[0]                       (36 x 1024 x 1024, K=64)
    gemm_nt<1><<<dim3(S_ / 64, S_ / 64, B_ * E_), 256, 0, stream>>>(
        proj, proj + D_, nullptr, out, D_, E_ * 2 * D_, E_ * 2 * D_, S_, E_,
        (long)S_ * E_ * 2 * D_, 2 * D_, (long)S_ * E_ * 2 * D_, 2 * D_,
        (long)E_ * S_ * S_, (long)S_ * S_, mask);

    // 11. ent_prior = rowmax(ent_logits), transposed to (B,S,E)
    rowmax_ent<<<B_ * E_ * S_, 256, 0, stream>>>(out, prior);

    // 12. rel_hidden = [enhanced, relu(prior @ prior_w.T + prior_b)]
    prior_concat<<<(int)(((long)MBS * 2 * H_) / 256), 256, 0, stream>>>(
        enh, prior, prw, prb, relh, (long)MBS * 2 * H_);

    // 13. rel projection                               (4096 x 1536, K=1536)
    gemm_nt<0><<<dim3((R_ * 2 * D_) / 64, MBS / 64, 1), 256, 0, stream>>>(
        relh, relw, relb, proj, 2 * H_, 2 * H_, 2 * H_, R_ * 2 * D_, 1,
        0, 0, 0, 0, 0, 0, nullptr);

    // 14. RoPE rotate rel projection in place
    rope_rot<<<(int)(((long)MBS * R_ * 64) / 256), 256, 0, stream>>>(
        proj, R_, (long)MBS * R_ * 64);

    // 15. rel logits -> d_out[1]                       (48 x 1024 x 1024, K=64)
    gemm_nt<1><<<dim3(S_ / 64, S_ / 64, B_ * R_), 256, 0, stream>>>(
        proj, proj + D_, nullptr, out + OUT_REL_OFF, D_, R_ * 2 * D_, R_ * 2 * D_, S_, R_,
        (long)S_ * R_ * 2 * D_, 2 * D_, (long)S_ * R_ * 2 * D_, 2 * D_,
        (long)R_ * S_ * S_, (long)S_ * S_, mask);

    (void)in_sizes; (void)n_in; (void)out_size; (void)ws_size;
}

// Round 3
// 337.538 us; speedup vs baseline: 3.7507x; 3.7507x over previous
//
#include <hip/hip_runtime.h>
#include <math.h>

#define H_   768
#define NH_  4
#define HD_  192
#define E_   9
#define R_   12
#define D_   64
#define B_   4
#define S_   1024
#define H3_  (3 * H_)
#define MBS_ (B_ * S_)

typedef unsigned short u16;
typedef __attribute__((ext_vector_type(4))) int   i32x4;
typedef __attribute__((ext_vector_type(4))) float f32x4;
typedef __attribute__((ext_vector_type(8))) unsigned short u16x8;

static const long OUT_REL_OFF = (long)B_ * E_ * S_ * S_;                    // 37,748,736
static const long OUT_ENH_OFF = OUT_REL_OFF + (long)B_ * R_ * S_ * S_;      // 88,080,384

__device__ __forceinline__ u16 f2bf(float f) {
    unsigned u = __builtin_bit_cast(unsigned, f);
    return (u16)((u + 0x7fffu + ((u >> 16) & 1u)) >> 16);
}
__device__ __forceinline__ float bf2f(u16 h) {
    return __builtin_bit_cast(float, (unsigned)h << 16);
}
__device__ __forceinline__ void gload16(const u16* g, u16* l) {
    __builtin_amdgcn_global_load_lds(
        (__attribute__((address_space(1))) void*)g,
        (__attribute__((address_space(3))) void*)l, 16, 0, 0);
}
__device__ __forceinline__ void mfma_bf16(f32x4& acc, i32x4 a, i32x4 b) {
    asm volatile("v_mfma_f32_16x16x32_bf16 %0, %1, %2, %0"
                 : "+v"(acc) : "v"(a), "v"(b));
}

// ---------------------------------------------------------------------------
// bf16 MFMA GEMM, NT: C[m,n] = sum_k A[m,k]*B[n,k]. BMxBN tile, BK=64,
// 256 thr = 4 waves (2x2), wave tile (BM/2)x(BN/2), 16x16x32 MFMA frags.
// EPI 0: +bias. EPI 1: logits epilogue (mask/tril/*0.125) fp32. EPI 2:
// *scale + keypad(-1e9) (scores). OBF: write bf16 else fp32.
// ---------------------------------------------------------------------------
template<int BM, int BN, int EPI, int OBF>
__global__ __launch_bounds__(256) void gemm_mfma(
    const u16* __restrict__ A, const u16* __restrict__ Bw,
    const float* __restrict__ bias, void* __restrict__ Cv,
    int K, int lda, int ldb, int ldc, int nh,
    long sAb, long sAh, long sBb, long sBh, long sCb, long sCh,
    const float* __restrict__ mask, float scale)
{
    constexpr int MI = BM / 32, NJ = BN / 32;
    const int z = blockIdx.z;
    const int zb = z / nh, zh = z - zb * nh;
    A  += zb * sAb + zh * sAh;
    Bw += zb * sBb + zh * sBh;
    const int m0 = blockIdx.y * BM, n0 = blockIdx.x * BN;

    __shared__ u16 lds[(BM + BN) * 64];
    u16* ldsA = lds;
    u16* ldsB = lds + BM * 64;

    const int t = threadIdx.x;
    const int lane = t & 63, wid = t >> 6;
    const int wr = wid >> 1, wc = wid & 1;
    const int l16 = lane & 15, l4 = lane >> 4;

    f32x4 acc[MI][NJ];
    #pragma unroll
    for (int mi = 0; mi < MI; ++mi)
        #pragma unroll
        for (int nj = 0; nj < NJ; ++nj)
            #pragma unroll
            for (int q = 0; q < 4; ++q) acc[mi][nj][q] = 0.0f;

    for (int k0 = 0; k0 < K; k0 += 64) {
        #pragma unroll
        for (int i = 0; i < BM / 32; ++i) {
            const int e = i * 256 + t;
            gload16(A + (long)(m0 + (e >> 3)) * lda + k0 + ((e & 7) << 3), ldsA + e * 8);
        }
        #pragma unroll
        for (int i = 0; i < BN / 32; ++i) {
            const int e = i * 256 + t;
            gload16(Bw + (long)(n0 + (e >> 3)) * ldb + k0 + ((e & 7) << 3), ldsB + e * 8);
        }
        __syncthreads();
        i32x4 af[MI][2], bfr[NJ][2];
        #pragma unroll
        for (int mi = 0; mi < MI; ++mi)
            #pragma unroll
            for (int kk = 0; kk < 2; ++kk)
                af[mi][kk] = *(const i32x4*)&ldsA[(wr * (BM / 2) + mi * 16 + l16) * 64 + kk * 32 + l4 * 8];
        #pragma unroll
        for (int nj = 0; nj < NJ; ++nj)
            #pragma unroll
            for (int kk = 0; kk < 2; ++kk)
                bfr[nj][kk] = *(const i32x4*)&ldsB[(wc * (BN / 2) + nj * 16 + l16) * 64 + kk * 32 + l4 * 8];
        #pragma unroll
        for (int kk = 0; kk < 2; ++kk)
            #pragma unroll
            for (int mi = 0; mi < MI; ++mi)
                #pragma unroll
                for (int nj = 0; nj < NJ; ++nj)
                    mfma_bf16(acc[mi][nj], af[mi][kk], bfr[nj][kk]);
        __syncthreads();
    }
    __builtin_amdgcn_sched_barrier(0);
    asm volatile("s_nop 7");
    asm volatile("s_nop 7");
    __builtin_amdgcn_sched_barrier(0);

    if (EPI != 0) mask += (long)zb * S_;
    const long cbase = zb * sCb + zh * sCh;
    #pragma unroll
    for (int mi = 0; mi < MI; ++mi) {
        #pragma unroll
        for (int nj = 0; nj < NJ; ++nj) {
            const int gn = n0 + wc * (BN / 2) + nj * 16 + l16;
            const float bv = (EPI == 0 && bias) ? bias[gn] : 0.0f;
            #pragma unroll
            for (int r = 0; r < 4; ++r) {
                const int gm = m0 + wr * (BM / 2) + mi * 16 + l4 * 4 + r;
                float v = acc[mi][nj][r];
                const long cidx = cbase + (long)gm * ldc + gn;
                if (EPI == 0) {
                    v += bv;
                } else if (EPI == 1) {
                    const float pad = mask[gn];
                    v = v * pad - (1.0f - pad) * 1e12f;
                    if (gm > gn) v -= 1e12f;
                    v *= 0.125f;
                } else {
                    v *= scale;
                    if (mask[gn] == 0.0f) v = -1e9f;
                }
                if (OBF) ((u16*)Cv)[cidx] = f2bf(v);
                else     ((float*)Cv)[cidx] = v;
            }
        }
    }
}

// ---------------------------------------------------------------------------
// Fused fp32->bf16 cast of hs + 5 weight matrices. 1024 elems per block.
// ---------------------------------------------------------------------------
__global__ __launch_bounds__(256) void cast_all(
    const float* __restrict__ hs, const float* __restrict__ ipw,
    const float* __restrict__ opw, const float* __restrict__ gw,
    const float* __restrict__ entw, const float* __restrict__ relw,
    u16* hs_o, u16* ipw_o, u16* opw_o, u16* gw_o, u16* entw_o, u16* relw_o)
{
    const int blk = blockIdx.x;
    const float* in; u16* out; long base;
    if      (blk < 3072) { in = hs;   out = hs_o;   base = (long)blk * 1024; }
    else if (blk < 4800) { in = ipw;  out = ipw_o;  base = (long)(blk - 3072) * 1024; }
    else if (blk < 5376) { in = opw;  out = opw_o;  base = (long)(blk - 4800) * 1024; }
    else if (blk < 5952) { in = gw;   out = gw_o;   base = (long)(blk - 5376) * 1024; }
    else if (blk < 6816) { in = entw; out = entw_o; base = (long)(blk - 5952) * 1024; }
    else                 { in = relw; out = relw_o; base = (long)(blk - 6816) * 1024; }
    const long idx = base + (long)threadIdx.x * 4;
    const float4 v = *(const float4*)&in[idx];
    ushort4 o; o.x = f2bf(v.x); o.y = f2bf(v.y); o.z = f2bf(v.z); o.w = f2bf(v.w);
    *(ushort4*)&out[idx] = o;
}

// ---------------------------------------------------------------------------
// V transpose: vt[(b,h)][d][s] = qkv_bf[(b,s)][1536 + h*192 + d]
// ---------------------------------------------------------------------------
__global__ __launch_bounds__(256) void transpose_v(
    const u16* __restrict__ qkv, u16* __restrict__ vt)
{
    __shared__ u16 tile[64][72];
    const int z = blockIdx.z, b = z >> 2, h = z & 3;
    const int d0 = blockIdx.x * 64, s0 = blockIdx.y * 64;
    const int t = threadIdx.x;
    const int r = t >> 2, c = (t & 3) << 4;
    const u16* src = qkv + ((long)(b * S_ + s0 + r)) * H3_ + 2 * H_ + h * HD_ + d0 + c;
    *(u16x8*)&tile[r][c]     = *(const u16x8*)src;
    *(u16x8*)&tile[r][c + 8] = *(const u16x8*)(src + 8);
    __syncthreads();
    u16 tmp[16];
    #pragma unroll
    for (int i = 0; i < 16; ++i) tmp[i] = tile[c + i][r];
    u16* dst = vt + ((long)z * HD_ + d0 + r) * S_ + s0 + c;
    *(u16x8*)dst       = *(u16x8*)&tmp[0];
    *(u16x8*)(dst + 8) = *(u16x8*)&tmp[8];
}

// ---------------------------------------------------------------------------
// In-place bf16 softmax over rows of 1024 (scale/mask already applied).
// ---------------------------------------------------------------------------
__global__ __launch_bounds__(256) void softmax_bf(u16* __restrict__ P)
{
    const long row = blockIdx.x;
    u16* p = P + row * (long)S_;
    const int tid = threadIdx.x;
    const ushort4 raw = *(const ushort4*)&p[tid << 2];
    float v0 = bf2f(raw.x), v1 = bf2f(raw.y), v2 = bf2f(raw.z), v3 = bf2f(raw.w);
    float mx = fmaxf(fmaxf(v0, v1), fmaxf(v2, v3));
    #pragma unroll
    for (int o = 32; o > 0; o >>= 1) mx = fmaxf(mx, __shfl_xor(mx, o, 64));
    __shared__ float sm[4];
    if ((tid & 63) == 0) sm[tid >> 6] = mx;
    __syncthreads();
    mx = fmaxf(fmaxf(sm[0], sm[1]), fmaxf(sm[2], sm[3]));
    v0 = __expf(v0 - mx); v1 = __expf(v1 - mx); v2 = __expf(v2 - mx); v3 = __expf(v3 - mx);
    float sum = v0 + v1 + v2 + v3;
    #pragma unroll
    for (int o = 32; o > 0; o >>= 1) sum += __shfl_xor(sum, o, 64);
    __syncthreads();
    if ((tid & 63) == 0) sm[tid >> 6] = sum;
    __syncthreads();
    sum = sm[0] + sm[1] + sm[2] + sm[3];
    const float inv = 1.0f / sum;
    ushort4 o4;
    o4.x = f2bf(v0 * inv); o4.y = f2bf(v1 * inv); o4.z = f2bf(v2 * inv); o4.w = f2bf(v3 * inv);
    *(ushort4*)&p[tid << 2] = o4;
}

// ---------------------------------------------------------------------------
// x = hs + sigmoid(gl)*ao ; LayerNorm -> enh fp32 (d_out) + enh bf16
// ---------------------------------------------------------------------------
__global__ __launch_bounds__(256) void gate_ln_bf(
    const float* __restrict__ hs, const u16* __restrict__ ao,
    const u16* __restrict__ gl, const float* __restrict__ g,
    const float* __restrict__ bta, float* __restrict__ enh, u16* __restrict__ enh_bf)
{
    const long row = blockIdx.x;
    const float* hrow = hs + row * H_;
    const u16* arow = ao + row * H_;
    const u16* grow = gl + row * H_;
    const int tid = threadIdx.x;
    float x[3];
    float sum = 0.0f, sq = 0.0f;
    #pragma unroll
    for (int i = 0; i < 3; ++i) {
        const int j = tid + i * 256;
        const float a = bf2f(arow[j]);
        const float gt = 1.0f / (1.0f + __expf(-bf2f(grow[j])));
        const float xv = hrow[j] + gt * a;
        x[i] = xv; sum += xv; sq += xv * xv;
    }
    __shared__ float sm[8];
    #pragma unroll
    for (int o = 32; o > 0; o >>= 1) {
        sum += __shfl_xor(sum, o, 64);
        sq  += __shfl_xor(sq, o, 64);
    }
    const int lane = tid & 63, wid = tid >> 6;
    if (lane == 0) { sm[wid] = sum; sm[4 + wid] = sq; }
    __syncthreads();
    sum = sm[0] + sm[1] + sm[2] + sm[3];
    sq  = sm[4] + sm[5] + sm[6] + sm[7];
    const float mu = sum * (1.0f / (float)H_);
    float var = sq * (1.0f / (float)H_) - mu * mu;
    var = fmaxf(var, 0.0f);
    const float inv = 1.0f / sqrtf(var + 1e-5f);
    #pragma unroll
    for (int i = 0; i < 3; ++i) {
        const int j = tid + i * 256;
        const float o = (x[i] - mu) * inv * g[j] + bta[j];
        enh[row * H_ + j] = o;
        enh_bf[row * H_ + j] = f2bf(o);
    }
}

// ---------------------------------------------------------------------------
// RoPE: read fp32 proj (rows of T*128), write rotated bf16. 1 thread = 1 pair.
// ---------------------------------------------------------------------------
__global__ __launch_bounds__(256) void rope_bf(
    const float* __restrict__ in, u16* __restrict__ out, int T, long nrows)
{
    const long gid = (long)blockIdx.x * 256 + threadIdx.x;
    if (gid >= nrows * 64) return;
    const long rowI = gid >> 6;
    const int pidx = (int)(gid & 63);
    const int half = pidx >> 5, ip = pidx & 31;
    const int c0 = half * 64 + ip * 2;
    const int s = (int)((rowI / T) & (S_ - 1));
    const float inv = exp2f(-(float)ip * 0.41524101186092503f); // 10000^(-ip/32)
    float sn, cs;
    __sincosf((float)s * inv, &sn, &cs);
    const float2 x = *(const float2*)&in[rowI * 128 + c0];
    const unsigned lo = f2bf(x.x * cs - x.y * sn);
    const unsigned hi = f2bf(x.y * cs + x.x * sn);
    *(unsigned*)&out[rowI * 128 + c0] = lo | (hi << 16);
}

// ---------------------------------------------------------------------------
// ent_prior rowmax, transposed write prior[(b*S+m)*E + t]
// ---------------------------------------------------------------------------
__global__ __launch_bounds__(256) void rowmax_ent(
    const float* __restrict__ ent, float* __restrict__ prior)
{
    const long row = blockIdx.x;             // (b*E + t)*S + m
    const float4 v = *(const float4*)&ent[row * (long)S_ + threadIdx.x * 4];
    float mx = fmaxf(fmaxf(v.x, v.y), fmaxf(v.z, v.w));
    #pragma unroll
    for (int o = 32; o > 0; o >>= 1) mx = fmaxf(mx, __shfl_xor(mx, o, 64));
    __shared__ float sm[4];
    const int tid = threadIdx.x;
    if ((tid & 63) == 0) sm[tid >> 6] = mx;
    __syncthreads();
    if (tid == 0) {
        mx = fmaxf(fmaxf(sm[0], sm[1]), fmaxf(sm[2], sm[3]));
        const long b = row / ((long)E_ * S_);
        const long rem = row - b * E_ * S_;
        const int tt = (int)(rem / S_);
        const int m = (int)(rem - (long)tt * S_);
        prior[((long)b * S_ + m) * E_ + tt] = mx;
    }
}

// ---------------------------------------------------------------------------
// relh = [enh_bf, bf16(relu(prior @ pw^T + pb))]
// ---------------------------------------------------------------------------
__global__ __launch_bounds__(256) void prior_concat_bf(
    const u16* __restrict__ enh, const float* __restrict__ prior,
    const float* __restrict__ pw, const float* __restrict__ pb, u16* __restrict__ relh)
{
    const long row = blockIdx.x;
    const int tid = threadIdx.x;
    const float* pr = prior + row * E_;
    float p[E_];
    #pragma unroll
    for (int e = 0; e < E_; ++e) p[e] = pr[e];
    u16* orow = relh + row * (2 * H_);
    const u16* erow = enh + row * H_;
    #pragma unroll
    for (int i = 0; i < 3; ++i) orow[tid + i * 256] = erow[tid + i * 256];
    #pragma unroll
    for (int i = 0; i < 3; ++i) {
        const int j = tid + i * 256;
        float a = pb[j];
        #pragma unroll
        for (int e = 0; e < E_; ++e) a = fmaf(p[e], pw[j * E_ + e], a);
        orow[H_ + j] = f2bf(fmaxf(a, 0.0f));
    }
}

// ---------------------------------------------------------------------------
extern "C" void kernel_launch(void* const* d_in, const int* in_sizes, int n_in,
                              void* d_out, int out_size, void* d_ws, size_t ws_size,
                              hipStream_t stream)
{
    const float* hs   = (const float*)d_in[0];
    const float* mask = (const float*)d_in[1];
    const float* ipw  = (const float*)d_in[2];
    const float* ipb  = (const float*)d_in[3];
    const float* opw  = (const float*)d_in[4];
    const float* opb  = (const float*)d_in[5];
    const float* gw   = (const float*)d_in[6];
    const float* gb   = (const float*)d_in[7];
    const float* lng  = (const float*)d_in[8];
    const float* lnb  = (const float*)d_in[9];
    const float* entw = (const float*)d_in[10];
    const float* entb = (const float*)d_in[11];
    const float* prw  = (const float*)d_in[12];
    const float* prb  = (const float*)d_in[13];
    const float* relw = (const float*)d_in[14];
    const float* relb = (const float*)d_in[15];
    float* out = (float*)d_out;
    char* base = (char*)d_ws;

    // ws layout (bytes, all 1KB-aligned); peak 102.6 MB
    u16* ipw_bf  = (u16*)(base + 0);          // 3,538,944
    u16* opw_bf  = (u16*)(base + 3538944);    // 1,179,648
    u16* gw_bf   = (u16*)(base + 4718592);    // 1,179,648
    u16* entw_bf = (u16*)(base + 5898240);    // 1,769,472
    u16* relw_bf = (u16*)(base + 7667712);    // 4,718,592
    u16* hs_bf   = (u16*)(base + 12386304);   // 6,291,456
    u16* qkv_bf  = (u16*)(base + 18677760);   // 18,874,368 (dead after QK/transpose)
    u16* vt_bf   = (u16*)(base + 37552128);   // 6,291,456  (dead after PV)
    u16* sc_bf   = (u16*)(base + 43843584);   // 33,554,432 (dead after PV)
    u16* ctx_bf  = (u16*)(base + 77398016);   // 6,291,456
    u16* ao_bf   = (u16*)(base + 83689472);   // 6,291,456
    u16* gl_bf   = (u16*)(base + 89980928);   // 6,291,456
    u16* enh_bf  = (u16*)(base + 96272384);   // 6,291,456
    float* proj  = (float*)(base + 18677760); // 25,165,824 (reuse qkv/vt region)
    u16* projr   = (u16*)(base + 43843584);   // 12,582,912 (reuse sc region)
    u16* relh_bf = (u16*)(base + 56426496);   // 12,582,912
    float* prior = (float*)(base + 69009408); //    147,456
    float* enh   = out + OUT_ENH_OFF;

    const float qscale = 0.07216878364870323f; // 1/sqrt(192)

    // 0. casts
    cast_all<<<9120, 256, 0, stream>>>(hs, ipw, opw, gw, entw, relw,
                                       hs_bf, ipw_bf, opw_bf, gw_bf, entw_bf, relw_bf);

    // 1. qkv = hs @ in_proj_w.T + b   (4096 x 2304, K=768)
    gemm_mfma<128,128,0,1><<<dim3(18, 32, 1), 256, 0, stream>>>(
        hs_bf, ipw_bf, ipb, qkv_bf, H_, H_, H_, H3_, 1,
        0,0,0,0,0,0, nullptr, 0.0f);

    // 1b. V transpose
    transpose_v<<<dim3(3, 16, 16), 256, 0, stream>>>(qkv_bf, vt_bf);

    // 2. scores = (Q K^T)/sqrt(HD) with keypad, bf16   (16 x 1024 x 1024, K=192)
    gemm_mfma<128,128,2,1><<<dim3(8, 8, B_ * NH_), 256, 0, stream>>>(
        qkv_bf, qkv_bf + H_, nullptr, sc_bf, HD_, H3_, H3_, S_, NH_,
        (long)S_ * H3_, HD_, (long)S_ * H3_, HD_,
        (long)NH_ * S_ * S_, (long)S_ * S_, mask, qscale);

    // 3. softmax in place (bf16)
    softmax_bf<<<B_ * NH_ * S_, 256, 0, stream>>>(sc_bf);

    // 4. ctx = P @ V   (16 x 1024 x 192, K=1024), BN=64
    gemm_mfma<128,64,0,1><<<dim3(3, 8, B_ * NH_), 256, 0, stream>>>(
        sc_bf, vt_bf, nullptr, ctx_bf, S_, S_, S_, H_, NH_,
        (long)NH_ * S_ * S_, (long)S_ * S_, (long)NH_ * HD_ * S_, (long)HD_ * S_,
        (long)S_ * H_, HD_, nullptr, 0.0f);

    // 5. attn_out = ctx @ out_proj.T + b   (4096 x 768, K=768)
    gemm_mfma<128,64,0,1><<<dim3(12, 32, 1), 256, 0, stream>>>(
        ctx_bf, opw_bf, opb, ao_bf, H_, H_, H_, H_, 1,
        0,0,0,0,0,0, nullptr, 0.0f);

    // 6. gate_lin = attn_out @ gate_w.T + b
    gemm_mfma<128,64,0,1><<<dim3(12, 32, 1), 256, 0, stream>>>(
        ao_bf, gw_bf, gb, gl_bf, H_, H_, H_, H_, 1,
        0,0,0,0,0,0, nullptr, 0.0f);

    // 7. enhanced = LN(hs + sigmoid(gl)*ao)
    gate_ln_bf<<<MBS_, 256, 0, stream>>>(hs, ao_bf, gl_bf, lng, lnb, enh, enh_bf);

    // 8. ent projection (4096 x 1152, K=768) -> fp32
    gemm_mfma<128,128,0,0><<<dim3(9, 32, 1), 256, 0, stream>>>(
        enh_bf, entw_bf, entb, proj, H_, H_, H_, E_ * 2 * D_, 1,
        0,0,0,0,0,0, nullptr, 0.0f);

    // 9. RoPE -> bf16
    rope_bf<<<(MBS_ * E_ * 64) / 256, 256, 0, stream>>>(proj, projr, E_, (long)MBS_ * E_);

    // 10. ent logits -> out[0]   (36 x 1024 x 1024, K=64)
    gemm_mfma<128,128,1,0><<<dim3(8, 8, B_ * E_), 256, 0, stream>>>(
        projr, projr + D_, nullptr, out, D_, E_ * 2 * D_, E_ * 2 * D_, S_, E_,
        (long)S_ * E_ * 2 * D_, 2 * D_, (long)S_ * E_ * 2 * D_, 2 * D_,
        (long)E_ * S_ * S_, (long)S_ * S_, mask, 0.0f);

    // 11. ent_prior rowmax (transposed)
    rowmax_ent<<<B_ * E_ * S_, 256, 0, stream>>>(out, prior);

    // 12. relh = [enh, relu(prior @ pw^T + pb)]
    prior_concat_bf<<<MBS_, 256, 0, stream>>>(enh_bf, prior, prw, prb, relh_bf);

    // 13. rel projection (4096 x 1536, K=1536) -> fp32
    gemm_mfma<128,128,0,0><<<dim3(12, 32, 1), 256, 0, stream>>>(
        relh_bf, relw_bf, relb, proj, 2 * H_, 2 * H_, 2 * H_, R_ * 2 * D_, 1,
        0,0,0,0,0,0, nullptr, 0.0f);

    // 14. RoPE -> bf16
    rope_bf<<<(MBS_ * R_ * 64) / 256, 256, 0, stream>>>(proj, projr, R_, (long)MBS_ * R_);

    // 15. rel logits -> out[1]   (48 x 1024 x 1024, K=64)
    gemm_mfma<128,128,1,0><<<dim3(8, 8, B_ * R_), 256, 0, stream>>>(
        projr, projr + D_, nullptr, out + OUT_REL_OFF, D_, R_ * 2 * D_, R_ * 2 * D_, S_, R_,
        (long)S_ * R_ * 2 * D_, 2 * D_, (long)S_ * R_ * 2 * D_, 2 * D_,
        (long)R_ * S_ * S_, (long)S_ * S_, mask, 0.0f);

    (void)in_sizes; (void)n_in; (void)out_size; (void)ws_size;
}

// Round 4
// 306.772 us; speedup vs baseline: 4.1269x; 1.1003x over previous
//
#include <hip/hip_runtime.h>
#include <math.h>

#define H_   768
#define NH_  4
#define HD_  192
#define E_   9
#define R_   12
#define D_   64
#define B_   4
#define S_   1024
#define H3_  (3 * H_)
#define MBS_ (B_ * S_)

typedef unsigned short u16;
typedef __attribute__((ext_vector_type(4))) int   i32x4;
typedef __attribute__((ext_vector_type(4))) float f32x4;
typedef __attribute__((ext_vector_type(8))) unsigned short u16x8;

static const long OUT_REL_OFF = (long)B_ * E_ * S_ * S_;                    // 37,748,736
static const long OUT_ENH_OFF = OUT_REL_OFF + (long)B_ * R_ * S_ * S_;      // 88,080,384

__device__ __forceinline__ u16 f2bf(float f) {
    unsigned u = __builtin_bit_cast(unsigned, f);
    return (u16)((u + 0x7fffu + ((u >> 16) & 1u)) >> 16);
}
__device__ __forceinline__ float bf2f(u16 h) {
    return __builtin_bit_cast(float, (unsigned)h << 16);
}
__device__ __forceinline__ void gload16(const u16* g, u16* l) {
    __builtin_amdgcn_global_load_lds(
        (__attribute__((address_space(1))) void*)g,
        (__attribute__((address_space(3))) void*)l, 16, 0, 0);
}
__device__ __forceinline__ void mfma_bf16(f32x4& acc, i32x4 a, i32x4 b) {
    asm volatile("v_mfma_f32_16x16x32_bf16 %0, %1, %2, %0"
                 : "+v"(acc) : "v"(a), "v"(b));
}

// ---------------------------------------------------------------------------
// bf16 MFMA GEMM, NT: C[m,n] = sum_k A[m,k]*B[n,k]. BMxBN tile, BK=64,
// 256 thr = 4 waves (2x2), wave tile (BM/2)x(BN/2), 16x16x32 MFMA frags.
// EPI 0: +bias, OBF selects bf16/fp32 out.
// EPI 1: logits epilogue (mask/tril/*0.125), fp32 out.
// EPI 2: *scale + keypad(-1e9), bf16 out (scores).
// EPI 3: EPI1 + per-row max partials -> pmax[(z*S+gm)*16 + bx*2+wc].
// EPI 4: +bias then fused RoPE rotation (pair via shfl_xor 1), bf16 out.
// ---------------------------------------------------------------------------
template<int BM, int BN, int EPI, int OBF>
__global__ __launch_bounds__(256) void gemm_mfma(
    const u16* __restrict__ A, const u16* __restrict__ Bw,
    const float* __restrict__ bias, void* __restrict__ Cv,
    int K, int lda, int ldb, int ldc, int nh,
    long sAb, long sAh, long sBb, long sBh, long sCb, long sCh,
    const float* __restrict__ mask, float scale, float* __restrict__ pmax)
{
    constexpr int MI = BM / 32, NJ = BN / 32;
    const int z = blockIdx.z;
    const int zb = z / nh, zh = z - zb * nh;
    A  += zb * sAb + zh * sAh;
    Bw += zb * sBb + zh * sBh;
    const int m0 = blockIdx.y * BM, n0 = blockIdx.x * BN;

    __shared__ u16 lds[(BM + BN) * 64];
    u16* ldsA = lds;
    u16* ldsB = lds + BM * 64;

    const int t = threadIdx.x;
    const int lane = t & 63, wid = t >> 6;
    const int wr = wid >> 1, wc = wid & 1;
    const int l16 = lane & 15, l4 = lane >> 4;

    f32x4 acc[MI][NJ];
    #pragma unroll
    for (int mi = 0; mi < MI; ++mi)
        #pragma unroll
        for (int nj = 0; nj < NJ; ++nj)
            #pragma unroll
            for (int q = 0; q < 4; ++q) acc[mi][nj][q] = 0.0f;

    for (int k0 = 0; k0 < K; k0 += 64) {
        #pragma unroll
        for (int i = 0; i < BM / 32; ++i) {
            const int e = i * 256 + t;
            gload16(A + (long)(m0 + (e >> 3)) * lda + k0 + ((e & 7) << 3), ldsA + e * 8);
        }
        #pragma unroll
        for (int i = 0; i < BN / 32; ++i) {
            const int e = i * 256 + t;
            gload16(Bw + (long)(n0 + (e >> 3)) * ldb + k0 + ((e & 7) << 3), ldsB + e * 8);
        }
        __syncthreads();
        i32x4 af[MI][2], bfr[NJ][2];
        #pragma unroll
        for (int mi = 0; mi < MI; ++mi)
            #pragma unroll
            for (int kk = 0; kk < 2; ++kk)
                af[mi][kk] = *(const i32x4*)&ldsA[(wr * (BM / 2) + mi * 16 + l16) * 64 + kk * 32 + l4 * 8];
        #pragma unroll
        for (int nj = 0; nj < NJ; ++nj)
            #pragma unroll
            for (int kk = 0; kk < 2; ++kk)
                bfr[nj][kk] = *(const i32x4*)&ldsB[(wc * (BN / 2) + nj * 16 + l16) * 64 + kk * 32 + l4 * 8];
        #pragma unroll
        for (int kk = 0; kk < 2; ++kk)
            #pragma unroll
            for (int mi = 0; mi < MI; ++mi)
                #pragma unroll
                for (int nj = 0; nj < NJ; ++nj)
                    mfma_bf16(acc[mi][nj], af[mi][kk], bfr[nj][kk]);
        __syncthreads();
    }
    __builtin_amdgcn_sched_barrier(0);
    asm volatile("s_nop 7");
    asm volatile("s_nop 7");
    __builtin_amdgcn_sched_barrier(0);

    if (EPI == 1 || EPI == 2 || EPI == 3) mask += (long)zb * S_;
    const long cbase = zb * sCb + zh * sCh;

    float rmx[MI][4];
    if (EPI == 3) {
        #pragma unroll
        for (int mi = 0; mi < MI; ++mi)
            #pragma unroll
            for (int r = 0; r < 4; ++r) rmx[mi][r] = -INFINITY;
    }

    #pragma unroll
    for (int mi = 0; mi < MI; ++mi) {
        #pragma unroll
        for (int nj = 0; nj < NJ; ++nj) {
            const int gn = n0 + wc * (BN / 2) + nj * 16 + l16;
            const float bv = ((EPI == 0 || EPI == 4) && bias) ? bias[gn] : 0.0f;
            float invf = 0.0f;
            if (EPI == 4) invf = exp2f(-(float)((gn & 63) >> 1) * 0.41524101186092503f);
            #pragma unroll
            for (int r = 0; r < 4; ++r) {
                const int gm = m0 + wr * (BM / 2) + mi * 16 + l4 * 4 + r;
                float v = acc[mi][nj][r];
                const long cidx = cbase + (long)gm * ldc + gn;
                if (EPI == 0) {
                    v += bv;
                    if (OBF) ((u16*)Cv)[cidx] = f2bf(v);
                    else     ((float*)Cv)[cidx] = v;
                } else if (EPI == 1 || EPI == 3) {
                    const float pad = mask[gn];
                    v = v * pad - (1.0f - pad) * 1e12f;
                    if (gm > gn) v -= 1e12f;
                    v *= 0.125f;
                    ((float*)Cv)[cidx] = v;
                    if (EPI == 3) rmx[mi][r] = fmaxf(rmx[mi][r], v);
                } else if (EPI == 2) {
                    v *= scale;
                    if (mask[gn] == 0.0f) v = -1e9f;
                    ((u16*)Cv)[cidx] = f2bf(v);
                } else { // EPI == 4
                    v += bv;
                    const int sp = gm & (S_ - 1);
                    float sn, cs;
                    __sincosf((float)sp * invf, &sn, &cs);
                    const float pv = __shfl_xor(v, 1, 64);
                    v = (gn & 1) ? fmaf(v, cs, pv * sn) : fmaf(v, cs, -pv * sn);
                    ((u16*)Cv)[cidx] = f2bf(v);
                }
            }
        }
    }

    if (EPI == 3) {
        #pragma unroll
        for (int mi = 0; mi < MI; ++mi) {
            #pragma unroll
            for (int r = 0; r < 4; ++r) {
                float m = rmx[mi][r];
                m = fmaxf(m, __shfl_xor(m, 1, 64));
                m = fmaxf(m, __shfl_xor(m, 2, 64));
                m = fmaxf(m, __shfl_xor(m, 4, 64));
                m = fmaxf(m, __shfl_xor(m, 8, 64));
                if (l16 == 0) {
                    const int gm = m0 + wr * (BM / 2) + mi * 16 + l4 * 4 + r;
                    pmax[((long)z * S_ + gm) * 16 + blockIdx.x * 2 + wc] = m;
                }
            }
        }
    }
}

// ---------------------------------------------------------------------------
// Fused fp32->bf16 cast of hs + 5 weight matrices. 1024 elems per block.
// ---------------------------------------------------------------------------
__global__ __launch_bounds__(256) void cast_all(
    const float* __restrict__ hs, const float* __restrict__ ipw,
    const float* __restrict__ opw, const float* __restrict__ gw,
    const float* __restrict__ entw, const float* __restrict__ relw,
    u16* hs_o, u16* ipw_o, u16* opw_o, u16* gw_o, u16* entw_o, u16* relw_o)
{
    const int blk = blockIdx.x;
    const float* in; u16* out; long base;
    if      (blk < 3072) { in = hs;   out = hs_o;   base = (long)blk * 1024; }
    else if (blk < 4800) { in = ipw;  out = ipw_o;  base = (long)(blk - 3072) * 1024; }
    else if (blk < 5376) { in = opw;  out = opw_o;  base = (long)(blk - 4800) * 1024; }
    else if (blk < 5952) { in = gw;   out = gw_o;   base = (long)(blk - 5376) * 1024; }
    else if (blk < 6816) { in = entw; out = entw_o; base = (long)(blk - 5952) * 1024; }
    else                 { in = relw; out = relw_o; base = (long)(blk - 6816) * 1024; }
    const long idx = base + (long)threadIdx.x * 4;
    const float4 v = *(const float4*)&in[idx];
    ushort4 o; o.x = f2bf(v.x); o.y = f2bf(v.y); o.z = f2bf(v.z); o.w = f2bf(v.w);
    *(ushort4*)&out[idx] = o;
}

// ---------------------------------------------------------------------------
// V transpose: vt[(b,h)][d][s] = qkv_bf[(b,s)][1536 + h*192 + d]
// ---------------------------------------------------------------------------
__global__ __launch_bounds__(256) void transpose_v(
    const u16* __restrict__ qkv, u16* __restrict__ vt)
{
    __shared__ u16 tile[64][72];
    const int z = blockIdx.z, b = z >> 2, h = z & 3;
    const int d0 = blockIdx.x * 64, s0 = blockIdx.y * 64;
    const int t = threadIdx.x;
    const int r = t >> 2, c = (t & 3) << 4;
    const u16* src = qkv + ((long)(b * S_ + s0 + r)) * H3_ + 2 * H_ + h * HD_ + d0 + c;
    *(u16x8*)&tile[r][c]     = *(const u16x8*)src;
    *(u16x8*)&tile[r][c + 8] = *(const u16x8*)(src + 8);
    __syncthreads();
    u16 tmp[16];
    #pragma unroll
    for (int i = 0; i < 16; ++i) tmp[i] = tile[c + i][r];
    u16* dst = vt + ((long)z * HD_ + d0 + r) * S_ + s0 + c;
    *(u16x8*)dst       = *(u16x8*)&tmp[0];
    *(u16x8*)(dst + 8) = *(u16x8*)&tmp[8];
}

// ---------------------------------------------------------------------------
// In-place bf16 softmax over rows of 1024 (scale/mask already applied).
// ---------------------------------------------------------------------------
__global__ __launch_bounds__(256) void softmax_bf(u16* __restrict__ P)
{
    const long row = blockIdx.x;
    u16* p = P + row * (long)S_;
    const int tid = threadIdx.x;
    const ushort4 raw = *(const ushort4*)&p[tid << 2];
    float v0 = bf2f(raw.x), v1 = bf2f(raw.y), v2 = bf2f(raw.z), v3 = bf2f(raw.w);
    float mx = fmaxf(fmaxf(v0, v1), fmaxf(v2, v3));
    #pragma unroll
    for (int o = 32; o > 0; o >>= 1) mx = fmaxf(mx, __shfl_xor(mx, o, 64));
    __shared__ float sm[4];
    if ((tid & 63) == 0) sm[tid >> 6] = mx;
    __syncthreads();
    mx = fmaxf(fmaxf(sm[0], sm[1]), fmaxf(sm[2], sm[3]));
    v0 = __expf(v0 - mx); v1 = __expf(v1 - mx); v2 = __expf(v2 - mx); v3 = __expf(v3 - mx);
    float sum = v0 + v1 + v2 + v3;
    #pragma unroll
    for (int o = 32; o > 0; o >>= 1) sum += __shfl_xor(sum, o, 64);
    __syncthreads();
    if ((tid & 63) == 0) sm[tid >> 6] = sum;
    __syncthreads();
    sum = sm[0] + sm[1] + sm[2] + sm[3];
    const float inv = 1.0f / sum;
    ushort4 o4;
    o4.x = f2bf(v0 * inv); o4.y = f2bf(v1 * inv); o4.z = f2bf(v2 * inv); o4.w = f2bf(v3 * inv);
    *(ushort4*)&p[tid << 2] = o4;
}

// ---------------------------------------------------------------------------
// x = hs + sigmoid(gl)*ao ; LayerNorm -> enh fp32 (d_out) + relh[:768] bf16
// ---------------------------------------------------------------------------
__global__ __launch_bounds__(256) void gate_ln_bf(
    const float* __restrict__ hs, const u16* __restrict__ ao,
    const u16* __restrict__ gl, const float* __restrict__ g,
    const float* __restrict__ bta, float* __restrict__ enh, u16* __restrict__ relh)
{
    const long row = blockIdx.x;
    const float* hrow = hs + row * H_;
    const u16* arow = ao + row * H_;
    const u16* grow = gl + row * H_;
    const int tid = threadIdx.x;
    float x[3];
    float sum = 0.0f, sq = 0.0f;
    #pragma unroll
    for (int i = 0; i < 3; ++i) {
        const int j = tid + i * 256;
        const float a = bf2f(arow[j]);
        const float gt = 1.0f / (1.0f + __expf(-bf2f(grow[j])));
        const float xv = hrow[j] + gt * a;
        x[i] = xv; sum += xv; sq += xv * xv;
    }
    __shared__ float sm[8];
    #pragma unroll
    for (int o = 32; o > 0; o >>= 1) {
        sum += __shfl_xor(sum, o, 64);
        sq  += __shfl_xor(sq, o, 64);
    }
    const int lane = tid & 63, wid = tid >> 6;
    if (lane == 0) { sm[wid] = sum; sm[4 + wid] = sq; }
    __syncthreads();
    sum = sm[0] + sm[1] + sm[2] + sm[3];
    sq  = sm[4] + sm[5] + sm[6] + sm[7];
    const float mu = sum * (1.0f / (float)H_);
    float var = sq * (1.0f / (float)H_) - mu * mu;
    var = fmaxf(var, 0.0f);
    const float inv = 1.0f / sqrtf(var + 1e-5f);
    #pragma unroll
    for (int i = 0; i < 3; ++i) {
        const int j = tid + i * 256;
        const float o = (x[i] - mu) * inv * g[j] + bta[j];
        enh[row * H_ + j] = o;
        relh[row * (2 * H_) + j] = f2bf(o);
    }
}

// ---------------------------------------------------------------------------
// prior[(b*S+m)*E + t] = max over 16 partials of pmax[((b*E+t)*S+m)*16 + i]
// ---------------------------------------------------------------------------
__global__ __launch_bounds__(256) void reduce_prior(
    const float* __restrict__ pmax, float* __restrict__ prior)
{
    const int idx = blockIdx.x * 256 + threadIdx.x;     // (b*E+t)*S + m
    const float4* p = (const float4*)(pmax + (long)idx * 16);
    float m = -INFINITY;
    #pragma unroll
    for (int i = 0; i < 4; ++i) {
        const float4 v = p[i];
        m = fmaxf(m, fmaxf(fmaxf(v.x, v.y), fmaxf(v.z, v.w)));
    }
    const int z = idx >> 10, mrow = idx & (S_ - 1);
    const int b = z / E_, t = z - b * E_;
    prior[((long)b * S_ + mrow) * E_ + t] = m;
}

// ---------------------------------------------------------------------------
// relh[:, 768:1536] = bf16(relu(prior @ pw^T + pb))
// ---------------------------------------------------------------------------
__global__ __launch_bounds__(256) void prior_feat_bf(
    const float* __restrict__ prior, const float* __restrict__ pw,
    const float* __restrict__ pb, u16* __restrict__ relh)
{
    const long row = blockIdx.x;
    const int tid = threadIdx.x;
    const float* pr = prior + row * E_;
    float p[E_];
    #pragma unroll
    for (int e = 0; e < E_; ++e) p[e] = pr[e];
    u16* orow = relh + row * (2 * H_) + H_;
    #pragma unroll
    for (int i = 0; i < 3; ++i) {
        const int j = tid + i * 256;
        float a = pb[j];
        #pragma unroll
        for (int e = 0; e < E_; ++e) a = fmaf(p[e], pw[j * E_ + e], a);
        orow[j] = f2bf(fmaxf(a, 0.0f));
    }
}

// ---------------------------------------------------------------------------
extern "C" void kernel_launch(void* const* d_in, const int* in_sizes, int n_in,
                              void* d_out, int out_size, void* d_ws, size_t ws_size,
                              hipStream_t stream)
{
    const float* hs   = (const float*)d_in[0];
    const float* mask = (const float*)d_in[1];
    const float* ipw  = (const float*)d_in[2];
    const float* ipb  = (const float*)d_in[3];
    const float* opw  = (const float*)d_in[4];
    const float* opb  = (const float*)d_in[5];
    const float* gw   = (const float*)d_in[6];
    const float* gb   = (const float*)d_in[7];
    const float* lng  = (const float*)d_in[8];
    const float* lnb  = (const float*)d_in[9];
    const float* entw = (const float*)d_in[10];
    const float* entb = (const float*)d_in[11];
    const float* prw  = (const float*)d_in[12];
    const float* prb  = (const float*)d_in[13];
    const float* relw = (const float*)d_in[14];
    const float* relb = (const float*)d_in[15];
    float* out = (float*)d_out;
    char* base = (char*)d_ws;

    // ws layout (bytes); peak 96,272,384 + 12,582,912 = ~96.3 MB region end
    u16* ipw_bf  = (u16*)(base + 0);          // 3,538,944
    u16* opw_bf  = (u16*)(base + 3538944);    // 1,179,648
    u16* gw_bf   = (u16*)(base + 4718592);    // 1,179,648
    u16* entw_bf = (u16*)(base + 5898240);    // 1,769,472
    u16* relw_bf = (u16*)(base + 7667712);    // 4,718,592
    u16* hs_bf   = (u16*)(base + 12386304);   // 6,291,456  [dead after qkv]
    u16* qkv_bf  = (u16*)(base + 18677760);   // 18,874,368 [dead after scores]
    u16* vt_bf   = (u16*)(base + 37552128);   // 6,291,456  [dead after PV]
    u16* sc_bf   = (u16*)(base + 43843584);   // 33,554,432 [dead after PV]
    u16* ctx_bf  = (u16*)(base + 77398016);   // 6,291,456
    u16* ao_bf   = (u16*)(base + 83689472);   // 6,291,456
    u16* gl_bf   = (u16*)(base + 89980928);   // 6,291,456
    u16* relh_bf = (u16*)(base + 18677760);   // 12,582,912 (reuse qkv region)
    u16* projr   = (u16*)(base + 37552128);   // 12,582,912 (reuse vt+sc region)
    float* pmax  = (float*)(base + 50135040); //  2,359,296 (reuse sc region)
    float* prior = (float*)(base + 52494336); //    147,456 (reuse sc region)
    float* enh   = out + OUT_ENH_OFF;

    const float qscale = 0.07216878364870323f; // 1/sqrt(192)

    // 0. casts
    cast_all<<<9120, 256, 0, stream>>>(hs, ipw, opw, gw, entw, relw,
                                       hs_bf, ipw_bf, opw_bf, gw_bf, entw_bf, relw_bf);

    // 1. qkv = hs @ in_proj_w.T + b   (4096 x 2304, K=768)
    gemm_mfma<128,128,0,1><<<dim3(18, 32, 1), 256, 0, stream>>>(
        hs_bf, ipw_bf, ipb, qkv_bf, H_, H_, H_, H3_, 1,
        0,0,0,0,0,0, nullptr, 0.0f, nullptr);

    // 1b. V transpose
    transpose_v<<<dim3(3, 16, 16), 256, 0, stream>>>(qkv_bf, vt_bf);

    // 2. scores = (Q K^T)/sqrt(HD) with keypad, bf16   (16 x 1024 x 1024, K=192)
    gemm_mfma<128,128,2,1><<<dim3(8, 8, B_ * NH_), 256, 0, stream>>>(
        qkv_bf, qkv_bf + H_, nullptr, sc_bf, HD_, H3_, H3_, S_, NH_,
        (long)S_ * H3_, HD_, (long)S_ * H3_, HD_,
        (long)NH_ * S_ * S_, (long)S_ * S_, mask, qscale, nullptr);

    // 3. softmax in place (bf16)
    softmax_bf<<<B_ * NH_ * S_, 256, 0, stream>>>(sc_bf);

    // 4. ctx = P @ V   (16 x 1024 x 192, K=1024), BN=64
    gemm_mfma<128,64,0,1><<<dim3(3, 8, B_ * NH_), 256, 0, stream>>>(
        sc_bf, vt_bf, nullptr, ctx_bf, S_, S_, S_, H_, NH_,
        (long)NH_ * S_ * S_, (long)S_ * S_, (long)NH_ * HD_ * S_, (long)HD_ * S_,
        (long)S_ * H_, HD_, nullptr, 0.0f, nullptr);

    // 5. attn_out = ctx @ out_proj.T + b   (4096 x 768, K=768)
    gemm_mfma<128,64,0,1><<<dim3(12, 32, 1), 256, 0, stream>>>(
        ctx_bf, opw_bf, opb, ao_bf, H_, H_, H_, H_, 1,
        0,0,0,0,0,0, nullptr, 0.0f, nullptr);

    // 6. gate_lin = attn_out @ gate_w.T + b
    gemm_mfma<128,64,0,1><<<dim3(12, 32, 1), 256, 0, stream>>>(
        ao_bf, gw_bf, gb, gl_bf, H_, H_, H_, H_, 1,
        0,0,0,0,0,0, nullptr, 0.0f, nullptr);

    // 7. enhanced = LN(hs + sigmoid(gl)*ao) -> enh fp32 + relh[:768]
    gate_ln_bf<<<MBS_, 256, 0, stream>>>(hs, ao_bf, gl_bf, lng, lnb, enh, relh_bf);

    // 8. ent projection + fused RoPE (4096 x 1152, K=768) -> projr bf16
    gemm_mfma<128,128,4,1><<<dim3(9, 32, 1), 256, 0, stream>>>(
        relh_bf, entw_bf, entb, projr, H_, 2 * H_, H_, E_ * 2 * D_, 1,
        0,0,0,0,0,0, nullptr, 0.0f, nullptr);

    // 10. ent logits + fused rowmax partials -> out[0], pmax
    gemm_mfma<128,128,3,0><<<dim3(8, 8, B_ * E_), 256, 0, stream>>>(
        projr, projr + D_, nullptr, out, D_, E_ * 2 * D_, E_ * 2 * D_, S_, E_,
        (long)S_ * E_ * 2 * D_, 2 * D_, (long)S_ * E_ * 2 * D_, 2 * D_,
        (long)E_ * S_ * S_, (long)S_ * S_, mask, 0.0f, pmax);

    // 11. prior = reduce(pmax), transposed
    reduce_prior<<<(B_ * E_ * S_) / 256, 256, 0, stream>>>(pmax, prior);

    // 12. relh[:, 768:] = relu(prior @ pw^T + pb)
    prior_feat_bf<<<MBS_, 256, 0, stream>>>(prior, prw, prb, relh_bf);

    // 13. rel projection + fused RoPE (4096 x 1536, K=1536) -> projr bf16
    gemm_mfma<128,128,4,1><<<dim3(12, 32, 1), 256, 0, stream>>>(
        relh_bf, relw_bf, relb, projr, 2 * H_, 2 * H_, 2 * H_, R_ * 2 * D_, 1,
        0,0,0,0,0,0, nullptr, 0.0f, nullptr);

    // 15. rel logits -> out[1]   (48 x 1024 x 1024, K=64)
    gemm_mfma<128,128,1,0><<<dim3(8, 8, B_ * R_), 256, 0, stream>>>(
        projr, projr + D_, nullptr, out + OUT_REL_OFF, D_, R_ * 2 * D_, R_ * 2 * D_, S_, R_,
        (long)S_ * R_ * 2 * D_, 2 * D_, (long)S_ * R_ * 2 * D_, 2 * D_,
        (long)R_ * S_ * S_, (long)S_ * S_, mask, 0.0f, nullptr);

    (void)in_sizes; (void)n_in; (void)out_size; (void)ws_size;
}

// Round 5
// 252.842 us; speedup vs baseline: 5.0071x; 1.2133x over previous
//
#include <hip/hip_runtime.h>
#include <math.h>

#define H_   768
#define NH_  4
#define HD_  192
#define E_   9
#define R_   12
#define D_   64
#define B_   4
#define S_   1024
#define H3_  (3 * H_)
#define MBS_ (B_ * S_)

typedef unsigned short u16;
typedef __attribute__((ext_vector_type(4))) int   i32x4;
typedef __attribute__((ext_vector_type(4))) float f32x4;
typedef __attribute__((ext_vector_type(8))) unsigned short u16x8;

static const long OUT_REL_OFF = (long)B_ * E_ * S_ * S_;                    // 37,748,736
static const long OUT_ENH_OFF = OUT_REL_OFF + (long)B_ * R_ * S_ * S_;      // 88,080,384

__device__ __forceinline__ u16 f2bf(float f) {
    unsigned u = __builtin_bit_cast(unsigned, f);
    return (u16)((u + 0x7fffu + ((u >> 16) & 1u)) >> 16);
}
__device__ __forceinline__ float bf2f(u16 h) {
    return __builtin_bit_cast(float, (unsigned)h << 16);
}
__device__ __forceinline__ void gload16(const u16* g, u16* l) {
    __builtin_amdgcn_global_load_lds(
        (__attribute__((address_space(1))) void*)g,
        (__attribute__((address_space(3))) void*)l, 16, 0, 0);
}
__device__ __forceinline__ void mfma_bf16(f32x4& acc, i32x4 a, i32x4 b) {
    asm volatile("v_mfma_f32_16x16x32_bf16 %0, %1, %2, %0"
                 : "+v"(acc) : "v"(a), "v"(b));
}

// ---------------------------------------------------------------------------
// bf16 MFMA GEMM, NT: C[m,n] = sum_k A[m,k]*B[n,k]. BMxBN tile, BK=64,
// 4 waves (2x2), 16x16x32 MFMA. LDS XOR-swizzled (granule ^= row&7) with
// pre-swizzled global source (gload_lds writes linearly). XCD-swizzled grid.
// EPI 0: +bias (OBF sel bf16/fp32 out)
// EPI 1: logits epilogue (mask/tril/*0.125), fp32 out
// EPI 3: EPI1 + per-row max partials -> aux[(z*S+gm)*16 + bx*2+wc]
// EPI 4: +bias then fused interleaved RoPE (pair via shfl_xor 1), bf16 out
// EPI 5: t=exp(v*scale) (0 if masked), bf16 out + row-sum partials -> aux
// EPI 6: v *= 1/rowsum (aux = psum in), bf16 out
// ---------------------------------------------------------------------------
template<int BM, int BN, int EPI, int OBF>
__global__ __launch_bounds__(256) void gemm_mfma(
    const u16* __restrict__ A, const u16* __restrict__ Bw,
    const float* __restrict__ bias, void* __restrict__ Cv,
    int K, int lda, int ldb, int ldc, int nh,
    long sAb, long sAh, long sBb, long sBh, long sCb, long sCh,
    const float* __restrict__ mask, float scale, float* __restrict__ aux)
{
    constexpr int MI = BM / 32, NJ = BN / 32;
    const int z = blockIdx.z;
    const int zb = z / nh, zh = z - zb * nh;
    A  += zb * sAb + zh * sAh;
    Bw += zb * sBb + zh * sBh;

    // XCD-aware bijective swizzle of (bx,by); all grids have nwg%8==0
    const int gx = gridDim.x, gy = gridDim.y;
    int id = blockIdx.y * gx + blockIdx.x;
    const int nwg = gx * gy;
    if ((nwg & 7) == 0) id = (id & 7) * (nwg >> 3) + (id >> 3);
    const int bx = id % gx, by = id / gx;
    const int m0 = by * BM, n0 = bx * BN;

    __shared__ u16 lds[(BM + BN) * 64];
    __shared__ float sminv[BM];
    u16* ldsA = lds;
    u16* ldsB = lds + BM * 64;

    const int t = threadIdx.x;
    const int lane = t & 63, wid = t >> 6;
    const int wr = wid >> 1, wc = wid & 1;
    const int l16 = lane & 15, l4 = lane >> 4;

    f32x4 acc[MI][NJ];
    #pragma unroll
    for (int mi = 0; mi < MI; ++mi)
        #pragma unroll
        for (int nj = 0; nj < NJ; ++nj)
            #pragma unroll
            for (int q = 0; q < 4; ++q) acc[mi][nj][q] = 0.0f;

    for (int k0 = 0; k0 < K; k0 += 64) {
        #pragma unroll
        for (int i = 0; i < BM / 32; ++i) {
            const int e = i * 256 + t;
            const int row = e >> 3;
            const int c = ((e & 7) ^ (row & 7)) << 3;      // pre-swizzled source
            gload16(A + (long)(m0 + row) * lda + k0 + c, ldsA + e * 8);
        }
        #pragma unroll
        for (int i = 0; i < BN / 32; ++i) {
            const int e = i * 256 + t;
            const int row = e >> 3;
            const int c = ((e & 7) ^ (row & 7)) << 3;
            gload16(Bw + (long)(n0 + row) * ldb + k0 + c, ldsB + e * 8);
        }
        __syncthreads();
        i32x4 af[MI][2], bfr[NJ][2];
        #pragma unroll
        for (int mi = 0; mi < MI; ++mi)
            #pragma unroll
            for (int kk = 0; kk < 2; ++kk) {
                const int row = wr * (BM / 2) + mi * 16 + l16;
                af[mi][kk] = *(const i32x4*)&ldsA[row * 64 + ((((kk << 2) + l4) ^ (row & 7)) << 3)];
            }
        #pragma unroll
        for (int nj = 0; nj < NJ; ++nj)
            #pragma unroll
            for (int kk = 0; kk < 2; ++kk) {
                const int row = wc * (BN / 2) + nj * 16 + l16;
                bfr[nj][kk] = *(const i32x4*)&ldsB[row * 64 + ((((kk << 2) + l4) ^ (row & 7)) << 3)];
            }
        #pragma unroll
        for (int kk = 0; kk < 2; ++kk)
            #pragma unroll
            for (int mi = 0; mi < MI; ++mi)
                #pragma unroll
                for (int nj = 0; nj < NJ; ++nj)
                    mfma_bf16(acc[mi][nj], af[mi][kk], bfr[nj][kk]);
        __syncthreads();
    }
    __builtin_amdgcn_sched_barrier(0);
    asm volatile("s_nop 7");
    asm volatile("s_nop 7");
    __builtin_amdgcn_sched_barrier(0);

    if (EPI == 1 || EPI == 3 || EPI == 5) mask += (long)zb * S_;
    const long cbase = zb * sCb + zh * sCh;

    if (EPI == 6) {   // preload 1/rowsum from 16 partials per row
        if (t < BM) {
            const float* pp = aux + ((long)z * S_ + m0 + t) * 16;
            float s = 0.0f;
            #pragma unroll
            for (int i = 0; i < 16; ++i) s += pp[i];
            sminv[t] = 1.0f / s;
        }
        __syncthreads();
    }

    float red[MI][4];
    if (EPI == 3 || EPI == 5) {
        #pragma unroll
        for (int mi = 0; mi < MI; ++mi)
            #pragma unroll
            for (int r = 0; r < 4; ++r) red[mi][r] = (EPI == 3) ? -INFINITY : 0.0f;
    }

    #pragma unroll
    for (int mi = 0; mi < MI; ++mi) {
        #pragma unroll
        for (int nj = 0; nj < NJ; ++nj) {
            const int gn = n0 + wc * (BN / 2) + nj * 16 + l16;
            const float bv = ((EPI == 0 || EPI == 4) && bias) ? bias[gn] : 0.0f;
            float invf = 0.0f;
            if (EPI == 4) invf = exp2f(-(float)((gn & 63) >> 1) * 0.41524101186092503f);
            #pragma unroll
            for (int r = 0; r < 4; ++r) {
                const int gm = m0 + wr * (BM / 2) + mi * 16 + l4 * 4 + r;
                float v = acc[mi][nj][r];
                const long cidx = cbase + (long)gm * ldc + gn;
                if (EPI == 0) {
                    v += bv;
                    if (OBF) ((u16*)Cv)[cidx] = f2bf(v);
                    else     ((float*)Cv)[cidx] = v;
                } else if (EPI == 1 || EPI == 3) {
                    const float pad = mask[gn];
                    v = v * pad - (1.0f - pad) * 1e12f;
                    if (gm > gn) v -= 1e12f;
                    v *= 0.125f;
                    ((float*)Cv)[cidx] = v;
                    if (EPI == 3) red[mi][r] = fmaxf(red[mi][r], v);
                } else if (EPI == 5) {
                    float tv = 0.0f;
                    if (mask[gn] != 0.0f) tv = __expf(v * scale);
                    ((u16*)Cv)[cidx] = f2bf(tv);
                    red[mi][r] += tv;
                } else if (EPI == 6) {
                    v *= sminv[gm - m0];
                    ((u16*)Cv)[cidx] = f2bf(v);
                } else { // EPI == 4
                    v += bv;
                    const int sp = gm & (S_ - 1);
                    float sn, cs;
                    __sincosf((float)sp * invf, &sn, &cs);
                    const float pv = __shfl_xor(v, 1, 64);
                    v = (gn & 1) ? fmaf(v, cs, pv * sn) : fmaf(v, cs, -pv * sn);
                    ((u16*)Cv)[cidx] = f2bf(v);
                }
            }
        }
    }

    if (EPI == 3 || EPI == 5) {
        #pragma unroll
        for (int mi = 0; mi < MI; ++mi) {
            #pragma unroll
            for (int r = 0; r < 4; ++r) {
                float m = red[mi][r];
                if (EPI == 3) {
                    m = fmaxf(m, __shfl_xor(m, 1, 64));
                    m = fmaxf(m, __shfl_xor(m, 2, 64));
                    m = fmaxf(m, __shfl_xor(m, 4, 64));
                    m = fmaxf(m, __shfl_xor(m, 8, 64));
                } else {
                    m += __shfl_xor(m, 1, 64);
                    m += __shfl_xor(m, 2, 64);
                    m += __shfl_xor(m, 4, 64);
                    m += __shfl_xor(m, 8, 64);
                }
                if (l16 == 0) {
                    const int gm = m0 + wr * (BM / 2) + mi * 16 + l4 * 4 + r;
                    aux[((long)z * S_ + gm) * 16 + bx * 2 + wc] = m;
                }
            }
        }
    }
}

// ---------------------------------------------------------------------------
// Fused fp32->bf16 cast of hs + 5 weight matrices. 1024 elems per block.
// ---------------------------------------------------------------------------
__global__ __launch_bounds__(256) void cast_all(
    const float* __restrict__ hs, const float* __restrict__ ipw,
    const float* __restrict__ opw, const float* __restrict__ gw,
    const float* __restrict__ entw, const float* __restrict__ relw,
    u16* hs_o, u16* ipw_o, u16* opw_o, u16* gw_o, u16* entw_o, u16* relw_o)
{
    const int blk = blockIdx.x;
    const float* in; u16* out; long base;
    if      (blk < 3072) { in = hs;   out = hs_o;   base = (long)blk * 1024; }
    else if (blk < 4800) { in = ipw;  out = ipw_o;  base = (long)(blk - 3072) * 1024; }
    else if (blk < 5376) { in = opw;  out = opw_o;  base = (long)(blk - 4800) * 1024; }
    else if (blk < 5952) { in = gw;   out = gw_o;   base = (long)(blk - 5376) * 1024; }
    else if (blk < 6816) { in = entw; out = entw_o; base = (long)(blk - 5952) * 1024; }
    else                 { in = relw; out = relw_o; base = (long)(blk - 6816) * 1024; }
    const long idx = base + (long)threadIdx.x * 4;
    const float4 v = *(const float4*)&in[idx];
    ushort4 o; o.x = f2bf(v.x); o.y = f2bf(v.y); o.z = f2bf(v.z); o.w = f2bf(v.w);
    *(ushort4*)&out[idx] = o;
}

// ---------------------------------------------------------------------------
// V transpose: vt[(b,h)][d][s] = qkv_bf[(b,s)][1536 + h*192 + d]
// ---------------------------------------------------------------------------
__global__ __launch_bounds__(256) void transpose_v(
    const u16* __restrict__ qkv, u16* __restrict__ vt)
{
    __shared__ u16 tile[64][72];
    const int z = blockIdx.z, b = z >> 2, h = z & 3;
    const int d0 = blockIdx.x * 64, s0 = blockIdx.y * 64;
    const int t = threadIdx.x;
    const int r = t >> 2, c = (t & 3) << 4;
    const u16* src = qkv + ((long)(b * S_ + s0 + r)) * H3_ + 2 * H_ + h * HD_ + d0 + c;
    *(u16x8*)&tile[r][c]     = *(const u16x8*)src;
    *(u16x8*)&tile[r][c + 8] = *(const u16x8*)(src + 8);
    __syncthreads();
    u16 tmp[16];
    #pragma unroll
    for (int i = 0; i < 16; ++i) tmp[i] = tile[c + i][r];
    u16* dst = vt + ((long)z * HD_ + d0 + r) * S_ + s0 + c;
    *(u16x8*)dst       = *(u16x8*)&tmp[0];
    *(u16x8*)(dst + 8) = *(u16x8*)&tmp[8];
}

// ---------------------------------------------------------------------------
// x = hs + sigmoid(gl)*ao ; LayerNorm -> enh fp32 (d_out) + relh[:768] bf16
// ao/gl packed in aogl rows of 1536: [0..768) = ao, [768..1536) = gl.
// ---------------------------------------------------------------------------
__global__ __launch_bounds__(256) void gate_ln_bf(
    const float* __restrict__ hs, const u16* __restrict__ aogl,
    const float* __restrict__ g, const float* __restrict__ bta,
    float* __restrict__ enh, u16* __restrict__ relh)
{
    const long row = blockIdx.x;
    const float* hrow = hs + row * H_;
    const u16* arow = aogl + row * (2 * H_);
    const int tid = threadIdx.x;
    float x[3];
    float sum = 0.0f, sq = 0.0f;
    #pragma unroll
    for (int i = 0; i < 3; ++i) {
        const int j = tid + i * 256;
        const float a = bf2f(arow[j]);
        const float gt = 1.0f / (1.0f + __expf(-bf2f(arow[H_ + j])));
        const float xv = hrow[j] + gt * a;
        x[i] = xv; sum += xv; sq += xv * xv;
    }
    __shared__ float sm[8];
    #pragma unroll
    for (int o = 32; o > 0; o >>= 1) {
        sum += __shfl_xor(sum, o, 64);
        sq  += __shfl_xor(sq, o, 64);
    }
    const int lane = tid & 63, wid = tid >> 6;
    if (lane == 0) { sm[wid] = sum; sm[4 + wid] = sq; }
    __syncthreads();
    sum = sm[0] + sm[1] + sm[2] + sm[3];
    sq  = sm[4] + sm[5] + sm[6] + sm[7];
    const float mu = sum * (1.0f / (float)H_);
    float var = sq * (1.0f / (float)H_) - mu * mu;
    var = fmaxf(var, 0.0f);
    const float inv = 1.0f / sqrtf(var + 1e-5f);
    #pragma unroll
    for (int i = 0; i < 3; ++i) {
        const int j = tid + i * 256;
        const float o = (x[i] - mu) * inv * g[j] + bta[j];
        enh[row * H_ + j] = o;
        relh[row * (2 * H_) + j] = f2bf(o);
    }
}

// ---------------------------------------------------------------------------
// Fused: prior[t] = max over 16 partials; relh[:,768:] = relu(prior@pw^T+pb)
// One block per (b,m) row.
// ---------------------------------------------------------------------------
__global__ __launch_bounds__(256) void prior_fused(
    const float* __restrict__ pmax, const float* __restrict__ pw,
    const float* __restrict__ pb, u16* __restrict__ relh)
{
    const int row = blockIdx.x;               // b*S + m
    const int b = row >> 10, m = row & (S_ - 1);
    __shared__ float pr[E_];
    const int tid = threadIdx.x;
    if (tid < E_) {
        const float* pp = pmax + ((long)(b * E_ + tid) * S_ + m) * 16;
        float mx = -INFINITY;
        #pragma unroll
        for (int i = 0; i < 16; ++i) mx = fmaxf(mx, pp[i]);
        pr[tid] = mx;
    }
    __syncthreads();
    float p[E_];
    #pragma unroll
    for (int e = 0; e < E_; ++e) p[e] = pr[e];
    u16* orow = relh + (long)row * (2 * H_) + H_;
    #pragma unroll
    for (int i = 0; i < 3; ++i) {
        const int j = tid + i * 256;
        float a = pb[j];
        #pragma unroll
        for (int e = 0; e < E_; ++e) a = fmaf(p[e], pw[j * E_ + e], a);
        orow[j] = f2bf(fmaxf(a, 0.0f));
    }
}

// ---------------------------------------------------------------------------
extern "C" void kernel_launch(void* const* d_in, const int* in_sizes, int n_in,
                              void* d_out, int out_size, void* d_ws, size_t ws_size,
                              hipStream_t stream)
{
    const float* hs   = (const float*)d_in[0];
    const float* mask = (const float*)d_in[1];
    const float* ipw  = (const float*)d_in[2];
    const float* ipb  = (const float*)d_in[3];
    const float* opw  = (const float*)d_in[4];
    const float* opb  = (const float*)d_in[5];
    const float* gw   = (const float*)d_in[6];
    const float* gb   = (const float*)d_in[7];
    const float* lng  = (const float*)d_in[8];
    const float* lnb  = (const float*)d_in[9];
    const float* entw = (const float*)d_in[10];
    const float* entb = (const float*)d_in[11];
    const float* prw  = (const float*)d_in[12];
    const float* prb  = (const float*)d_in[13];
    const float* relw = (const float*)d_in[14];
    const float* relb = (const float*)d_in[15];
    float* out = (float*)d_out;
    char* base = (char*)d_ws;

    // ws layout (bytes)
    u16* ipw_bf  = (u16*)(base + 0);          // 3,538,944
    u16* opw_bf  = (u16*)(base + 3538944);    // 1,179,648  } contiguous pair ->
    u16* gw_bf   = (u16*)(base + 4718592);    // 1,179,648  } combined [1536][768]
    u16* entw_bf = (u16*)(base + 5898240);    // 1,769,472
    u16* relw_bf = (u16*)(base + 7667712);    // 4,718,592
    u16* hs_bf   = (u16*)(base + 12386304);   // 6,291,456  [dead after qkv]
    u16* qkv_bf  = (u16*)(base + 18677760);   // 18,874,368 [dead after scores]
    u16* vt_bf   = (u16*)(base + 37552128);   // 6,291,456  [dead after PV]
    u16* sc_bf   = (u16*)(base + 43843584);   // 33,554,432 [dead after PV]
    u16* ctx_bf  = (u16*)(base + 77398016);   // 6,291,456
    u16* aogl_bf = (u16*)(base + 83689472);   // 12,582,912
    float* bias2 = (float*)(base + 96272384); //      6,144 (opb|gb)
    float* psum  = (float*)(base + 96280576); //  1,048,576
    float* pmax  = (float*)(base + 97329152); //  2,359,296
    u16* relh_bf = (u16*)(base + 18677760);   // 12,582,912 (reuse qkv region)
    u16* projr   = (u16*)(base + 37552128);   // 12,582,912 (reuse vt+sc region)
    float* enh   = out + OUT_ENH_OFF;

    const float qscale = 0.07216878364870323f; // 1/sqrt(192)

    // combined out_proj|gate bias
    hipMemcpyAsync(bias2, opb, H_ * sizeof(float), hipMemcpyDeviceToDevice, stream);
    hipMemcpyAsync(bias2 + H_, gb, H_ * sizeof(float), hipMemcpyDeviceToDevice, stream);

    // 0. casts
    cast_all<<<9120, 256, 0, stream>>>(hs, ipw, opw, gw, entw, relw,
                                       hs_bf, ipw_bf, opw_bf, gw_bf, entw_bf, relw_bf);

    // 1. qkv = hs @ in_proj_w.T + b   (4096 x 2304, K=768)
    gemm_mfma<128,128,0,1><<<dim3(18, 32, 1), 256, 0, stream>>>(
        hs_bf, ipw_bf, ipb, qkv_bf, H_, H_, H_, H3_, 1,
        0,0,0,0,0,0, nullptr, 0.0f, nullptr);

    // 2. V transpose
    transpose_v<<<dim3(3, 16, 16), 256, 0, stream>>>(qkv_bf, vt_bf);

    // 3. scores: t = exp(QK^T/sqrt(HD)) (masked->0), bf16 + row-sum partials
    gemm_mfma<128,128,5,1><<<dim3(8, 8, B_ * NH_), 256, 0, stream>>>(
        qkv_bf, qkv_bf + H_, nullptr, sc_bf, HD_, H3_, H3_, S_, NH_,
        (long)S_ * H3_, HD_, (long)S_ * H3_, HD_,
        (long)NH_ * S_ * S_, (long)S_ * S_, mask, qscale, psum);

    // 4. ctx = (T @ V) / rowsum   (16 x 1024 x 192, K=1024)
    gemm_mfma<128,64,6,1><<<dim3(3, 8, B_ * NH_), 256, 0, stream>>>(
        sc_bf, vt_bf, nullptr, ctx_bf, S_, S_, S_, H_, NH_,
        (long)NH_ * S_ * S_, (long)S_ * S_, (long)NH_ * HD_ * S_, (long)HD_ * S_,
        (long)S_ * H_, HD_, nullptr, 0.0f, psum);

    // 5. [attn_out | gate_lin] = ctx @ [opw|gw]^T + [opb|gb]  (4096 x 1536, K=768)
    gemm_mfma<128,128,0,1><<<dim3(12, 32, 1), 256, 0, stream>>>(
        ctx_bf, opw_bf, bias2, aogl_bf, H_, H_, H_, 2 * H_, 1,
        0,0,0,0,0,0, nullptr, 0.0f, nullptr);

    // 6. enhanced = LN(hs + sigmoid(gl)*ao) -> enh fp32 + relh[:768]
    gate_ln_bf<<<MBS_, 256, 0, stream>>>(hs, aogl_bf, lng, lnb, enh, relh_bf);

    // 7. ent projection + fused RoPE (4096 x 1152, K=768) -> projr bf16
    gemm_mfma<128,128,4,1><<<dim3(9, 32, 1), 256, 0, stream>>>(
        relh_bf, entw_bf, entb, projr, H_, 2 * H_, H_, E_ * 2 * D_, 1,
        0,0,0,0,0,0, nullptr, 0.0f, nullptr);

    // 8. ent logits + fused rowmax partials -> out[0], pmax
    gemm_mfma<128,128,3,0><<<dim3(8, 8, B_ * E_), 256, 0, stream>>>(
        projr, projr + D_, nullptr, out, D_, E_ * 2 * D_, E_ * 2 * D_, S_, E_,
        (long)S_ * E_ * 2 * D_, 2 * D_, (long)S_ * E_ * 2 * D_, 2 * D_,
        (long)E_ * S_ * S_, (long)S_ * S_, mask, 0.0f, pmax);

    // 9. prior reduce + feat -> relh[:, 768:]
    prior_fused<<<MBS_, 256, 0, stream>>>(pmax, prw, prb, relh_bf);

    // 10. rel projection + fused RoPE (4096 x 1536, K=1536) -> projr bf16
    gemm_mfma<128,128,4,1><<<dim3(12, 32, 1), 256, 0, stream>>>(
        relh_bf, relw_bf, relb, projr, 2 * H_, 2 * H_, 2 * H_, R_ * 2 * D_, 1,
        0,0,0,0,0,0, nullptr, 0.0f, nullptr);

    // 11. rel logits -> out[1]   (48 x 1024 x 1024, K=64)
    gemm_mfma<128,128,1,0><<<dim3(8, 8, B_ * R_), 256, 0, stream>>>(
        projr, projr + D_, nullptr, out + OUT_REL_OFF, D_, R_ * 2 * D_, R_ * 2 * D_, S_, R_,
        (long)S_ * R_ * 2 * D_, 2 * D_, (long)S_ * R_ * 2 * D_, 2 * D_,
        (long)R_ * S_ * S_, (long)S_ * S_, mask, 0.0f, nullptr);

    (void)in_sizes; (void)n_in; (void)out_size; (void)ws_size;
}